// Round 2
// baseline (659.660 us; speedup 1.0000x reference)
//
#include <hip/hip_runtime.h>
#include <math.h>

// Problem constants (fixed by reference setup_inputs)
#define B_ 16
#define C_ 512
#define N_ 4096   // 64*64
#define K_ 64

// Workspace layout (float offsets). Total = 655360 + 524288 floats = ~4.7 MB.
#define OFF_PCOMB   0         // [C][128]: per c: inv_s2[k 0..63] | -2*a*inv_s2[k 0..63]
#define OFF_INVSIG  65536     // [K][C]  1/sigma
#define OFF_CONST   98304     // [K]     sum_c anchor^2/sigma^2
#define OFF_WSUM    98368     // [B][K]
#define OFF_GSUM    99392     // [B]
#define OFF_WX      131072    // [B][K][C]  aggregation accumulator (atomic)
#define OFF_NODES   655360    // [B][K][C]  intra-normalized nodes

// ---------------------------------------------------------------- kernel 1
// Per-k parameter prep + zero the atomic accumulators.
__global__ void k_prep(const float* __restrict__ anchor,
                       const float* __restrict__ sraw,
                       float* __restrict__ pcomb,
                       float* __restrict__ invsig,
                       float* __restrict__ constk,
                       float* __restrict__ wsum,
                       float* __restrict__ gsum,
                       float* __restrict__ wx) {
  const int k = blockIdx.x;
  const int tid = threadIdx.x;
  float partial = 0.f;
#pragma unroll
  for (int r = 0; r < 2; r++) {
    int c = r * 256 + tid;
    float a = anchor[k * C_ + c];
    float s = 1.f / (1.f + __expf(-sraw[k * C_ + c]));   // sigmoid
    float is = 1.f / s;
    float is2 = is * is;
    pcomb[c * 128 + k] = is2;
    pcomb[c * 128 + 64 + k] = -2.f * a * is2;
    invsig[k * C_ + c] = is;
    partial = fmaf(a * a, is2, partial);
  }
  float v = partial;
#pragma unroll
  for (int off = 32; off; off >>= 1) v += __shfl_down(v, off);
  __shared__ float red[4];
  if ((tid & 63) == 0) red[tid >> 6] = v;
  __syncthreads();
  if (tid == 0) constk[k] = red[0] + red[1] + red[2] + red[3];
  // zero atomic accumulators (stream-ordered before users)
  for (int i = tid; i < 8192; i += 256) wx[(size_t)k * 8192 + i] = 0.f;
  if (k == 0) {
    for (int i = tid; i < B_ * K_; i += 256) wsum[i] = 0.f;
    if (tid < B_) gsum[tid] = 0.f;
  }
}

// ---------------------------------------------------------------- kernel 2
// LDS-tiled fp32 "GEMM" for d2 + fused softmax over K + w_sum atomics.
// grid (N/128, B), block 256. Thread tile: 4 n x 8 k.
__global__ __launch_bounds__(256) void k_dist(
    const float* __restrict__ x,
    const float* __restrict__ pcomb,
    const float* __restrict__ constk,
    float* __restrict__ soft,
    float* __restrict__ wsum) {
  const int b = blockIdx.y;
  const int n0blk = blockIdx.x * 128;
  const int tid = threadIdx.x;
  const int tn = tid & 31;      // n = n0blk + 4*tn + i
  const int tk = tid >> 5;      // k = 8*tk + j
  __shared__ float xsh[32][128];   // [c-chunk][n-tile]
  __shared__ float psh[32][128];   // [c-chunk][inv_s2 64 | -2a*inv_s2 64]
  __shared__ float red[8][128];    // softmax cross-tk exchange
  __shared__ float csh[64];
  if (tid < 64) csh[tid] = constk[tid];

  const float* xb = x + (size_t)b * ((size_t)C_ * N_) + n0blk;

  float acc[4][8];
#pragma unroll
  for (int i = 0; i < 4; i++)
#pragma unroll
    for (int j = 0; j < 8; j++) acc[i][j] = 0.f;

  float4 xreg[4], preg[4];
  // prefetch c-chunk 0
#pragma unroll
  for (int i = 0; i < 4; i++) {
    int flat = tid + i * 256;
    int row = flat >> 5, col = (flat & 31) * 4;
    xreg[i] = *(const float4*)&xb[(size_t)row * N_ + col];
    preg[i] = *(const float4*)&pcomb[row * 128 + col];
  }

  for (int c0 = 0; c0 < C_; c0 += 32) {
#pragma unroll
    for (int i = 0; i < 4; i++) {
      int flat = tid + i * 256;
      int row = flat >> 5, col = (flat & 31) * 4;
      *(float4*)&xsh[row][col] = xreg[i];
      *(float4*)&psh[row][col] = preg[i];
    }
    __syncthreads();
    if (c0 + 32 < C_) {
#pragma unroll
      for (int i = 0; i < 4; i++) {
        int flat = tid + i * 256;
        int row = flat >> 5, col = (flat & 31) * 4;
        xreg[i] = *(const float4*)&xb[(size_t)(c0 + 32 + row) * N_ + col];
        preg[i] = *(const float4*)&pcomb[(c0 + 32 + row) * 128 + col];
      }
    }
#pragma unroll 4
    for (int cc = 0; cc < 32; cc++) {
      float4 xv = *(const float4*)&xsh[cc][tn * 4];
      float4 p0 = *(const float4*)&psh[cc][tk * 8];
      float4 p1 = *(const float4*)&psh[cc][tk * 8 + 4];
      float4 q0 = *(const float4*)&psh[cc][64 + tk * 8];
      float4 q1 = *(const float4*)&psh[cc][64 + tk * 8 + 4];
      float xa[4] = {xv.x, xv.y, xv.z, xv.w};
      float pi[8] = {p0.x, p0.y, p0.z, p0.w, p1.x, p1.y, p1.z, p1.w};
      float pa[8] = {q0.x, q0.y, q0.z, q0.w, q1.x, q1.y, q1.z, q1.w};
#pragma unroll
      for (int i = 0; i < 4; i++) {
        float x2 = xa[i] * xa[i];
#pragma unroll
        for (int j = 0; j < 8; j++)
          acc[i][j] = fmaf(x2, pi[j], fmaf(xa[i], pa[j], acc[i][j]));
      }
    }
    __syncthreads();
  }

  // ---- softmax over k (64) per n ----
  float m[4];
#pragma unroll
  for (int i = 0; i < 4; i++) m[i] = -3.4e38f;
#pragma unroll
  for (int i = 0; i < 4; i++)
#pragma unroll
    for (int j = 0; j < 8; j++) {
      float l = -0.5f * (acc[i][j] + csh[tk * 8 + j]);
      acc[i][j] = l;
      m[i] = fmaxf(m[i], l);
    }
  *(float4*)&red[tk][tn * 4] = make_float4(m[0], m[1], m[2], m[3]);
  __syncthreads();
#pragma unroll
  for (int i = 0; i < 4; i++) {
    float mm = m[i];
#pragma unroll
    for (int t = 0; t < 8; t++) mm = fmaxf(mm, red[t][tn * 4 + i]);
    m[i] = mm;
  }
  __syncthreads();
  float s[4] = {0.f, 0.f, 0.f, 0.f};
#pragma unroll
  for (int i = 0; i < 4; i++)
#pragma unroll
    for (int j = 0; j < 8; j++) {
      float e = __expf(acc[i][j] - m[i]);
      acc[i][j] = e;
      s[i] += e;
    }
  *(float4*)&red[tk][tn * 4] = make_float4(s[0], s[1], s[2], s[3]);
  __syncthreads();
#pragma unroll
  for (int i = 0; i < 4; i++) {
    float ss = 0.f;
#pragma unroll
    for (int t = 0; t < 8; t++) ss += red[t][tn * 4 + i];
    s[i] = 1.f / ss;
  }

  // ---- write soft + wsum ----
  float* op = soft + ((size_t)(b * K_ + tk * 8)) * N_ + n0blk + tn * 4;
#pragma unroll
  for (int j = 0; j < 8; j++) {
    float w0 = acc[0][j] * s[0];
    float w1 = acc[1][j] * s[1];
    float w2 = acc[2][j] * s[2];
    float w3 = acc[3][j] * s[3];
    *(float4*)&op[(size_t)j * N_] = make_float4(w0, w1, w2, w3);
    float v = w0 + w1 + w2 + w3;
#pragma unroll
    for (int off = 16; off; off >>= 1) v += __shfl_down(v, off);
    if ((tid & 31) == 0) atomicAdd(&wsum[b * K_ + tk * 8 + j], v);
  }
}

// ---------------------------------------------------------------- kernel 3
// Aggregation GEMM: wx[b,k,c] += sum_n soft[b,k,n] * x[b,c,n]
// grid (C/128, 16 n-splits, B), block 256. Thread tile 4k x 8c.
// Register-prefetched staging to hide strided global load latency.
__global__ __launch_bounds__(256) void k_agg(const float* __restrict__ x,
                                             const float* __restrict__ soft,
                                             float* __restrict__ wx) {
  const int ct = blockIdx.x;        // c0 = ct*128
  const int nt = blockIdx.y;        // n range [nt*256, nt*256+256)
  const int b = blockIdx.z;
  const int tid = threadIdx.x;
  const int tk = tid >> 4;          // 0..15 -> k = 4*tk
  const int tc = tid & 15;          // 0..15 -> c = 8*tc
  __shared__ float wsh[32][68];     // pads keep rows 16B-aligned
  __shared__ float xsh[32][132];
  float acc[4][8];
#pragma unroll
  for (int i = 0; i < 4; i++)
#pragma unroll
    for (int j = 0; j < 8; j++) acc[i][j] = 0.f;

  const float* wb = soft + (size_t)b * K_ * N_ + nt * 256;
  const float* xb = x + ((size_t)b * C_ + ct * 128) * (size_t)N_ + nt * 256;
  const int ni = tid & 31, rr = tid >> 5;   // stage: 32 n x (8|16) rows

  float wreg[8], xreg[16];
#pragma unroll
  for (int r = 0; r < 8; r++) wreg[r] = wb[(size_t)(rr + r * 8) * N_ + ni];
#pragma unroll
  for (int r = 0; r < 16; r++) xreg[r] = xb[(size_t)(rr + r * 8) * N_ + ni];

  for (int n0 = 0; n0 < 256; n0 += 32) {
#pragma unroll
    for (int r = 0; r < 8; r++) wsh[ni][rr + r * 8] = wreg[r];
#pragma unroll
    for (int r = 0; r < 16; r++) xsh[ni][rr + r * 8] = xreg[r];
    __syncthreads();
    if (n0 + 32 < 256) {
#pragma unroll
      for (int r = 0; r < 8; r++)
        wreg[r] = wb[(size_t)(rr + r * 8) * N_ + n0 + 32 + ni];
#pragma unroll
      for (int r = 0; r < 16; r++)
        xreg[r] = xb[(size_t)(rr + r * 8) * N_ + n0 + 32 + ni];
    }
#pragma unroll 4
    for (int n = 0; n < 32; n++) {
      float wv[4], xv[8];
#pragma unroll
      for (int i = 0; i < 4; i++) wv[i] = wsh[n][tk * 4 + i];
#pragma unroll
      for (int j = 0; j < 8; j++) xv[j] = xsh[n][tc * 8 + j];
#pragma unroll
      for (int i = 0; i < 4; i++)
#pragma unroll
        for (int j = 0; j < 8; j++)
          acc[i][j] = fmaf(wv[i], xv[j], acc[i][j]);
    }
    __syncthreads();
  }
  float* wxp = wx + ((size_t)b * K_) * C_ + ct * 128;
#pragma unroll
  for (int i = 0; i < 4; i++)
#pragma unroll
    for (int j = 0; j < 8; j++)
      atomicAdd(&wxp[(size_t)(tk * 4 + i) * C_ + tc * 8 + j], acc[i][j]);
}

// ---------------------------------------------------------------- kernel 4
// nodes = (wx - wsum*anchor)/sigma/(wsum+eps); intra L2-norm; global sumsq.
// grid (K, B), block 128.
__global__ void k_nodes(const float* __restrict__ wx,
                        const float* __restrict__ wsum,
                        const float* __restrict__ anchor,
                        const float* __restrict__ invsig,
                        float* __restrict__ nodes,
                        float* __restrict__ gsum) {
  const int k = blockIdx.x, b = blockIdx.y;
  const int tid = threadIdx.x;
  float wsv = wsum[b * K_ + k];
  float winv = 1.f / (wsv + 1e-9f);
  float vals[4];
  float local = 0.f;
#pragma unroll
  for (int r = 0; r < 4; r++) {
    int c = r * 128 + tid;
    float w = wx[((size_t)(b * K_) + k) * C_ + c];
    float v = (w - wsv * anchor[k * C_ + c]) * invsig[k * C_ + c] * winv;
    vals[r] = v;
    local = fmaf(v, v, local);
  }
  float v = local;
#pragma unroll
  for (int off = 32; off; off >>= 1) v += __shfl_down(v, off);
  __shared__ float red[2];
  if ((tid & 63) == 0) red[tid >> 6] = v;
  __syncthreads();
  float sumsq = red[0] + red[1];
  float norm = sqrtf(sumsq);
  float scale = 1.f / fmaxf(norm, 1e-12f);
#pragma unroll
  for (int r = 0; r < 4; r++) {
    int c = r * 128 + tid;
    nodes[((size_t)(b * K_) + k) * C_ + c] = vals[r] * scale;
  }
  if (tid == 0) atomicAdd(&gsum[b], sumsq * scale * scale);
}

// ---------------------------------------------------------------- kernel 5
// Global L2 scale + write out0 ([B][K*C] flat == reference reshape(B,C,K)).
__global__ void k_final(const float* __restrict__ nodes,
                        const float* __restrict__ gsum,
                        float* __restrict__ out0) {
  for (int i = blockIdx.x * 256 + threadIdx.x; i < B_ * K_ * C_;
       i += gridDim.x * 256) {
    int b = i >> 15;  // K_*C_ = 32768
    out0[i] = nodes[i] * (1.f / fmaxf(sqrtf(gsum[b]), 1e-12f));
  }
}

// ---------------------------------------------------------------- launch
extern "C" void kernel_launch(void* const* d_in, const int* in_sizes, int n_in,
                              void* d_out, int out_size, void* d_ws, size_t ws_size,
                              hipStream_t stream) {
  const float* x = (const float*)d_in[0];       // [B,C,H,W]
  const float* anchor = (const float*)d_in[1];  // [K,C]
  const float* sraw = (const float*)d_in[2];    // [K,C]
  float* out0 = (float*)d_out;                          // [B,C,K] flat
  float* soft = out0 + (size_t)B_ * C_ * K_;            // [B,K,N]
  float* ws = (float*)d_ws;

  float* pcomb = ws + OFF_PCOMB;
  float* invsig = ws + OFF_INVSIG;
  float* constk = ws + OFF_CONST;
  float* wsum = ws + OFF_WSUM;
  float* gsum = ws + OFF_GSUM;
  float* wx = ws + OFF_WX;
  float* nodes = ws + OFF_NODES;

  k_prep<<<K_, 256, 0, stream>>>(anchor, sraw, pcomb, invsig, constk,
                                 wsum, gsum, wx);
  k_dist<<<dim3(N_ / 128, B_), 256, 0, stream>>>(x, pcomb, constk, soft, wsum);
  k_agg<<<dim3(C_ / 128, 16, B_), 256, 0, stream>>>(x, soft, wx);
  k_nodes<<<dim3(K_, B_), 128, 0, stream>>>(wx, wsum, anchor, invsig, nodes,
                                            gsum);
  k_final<<<512, 256, 0, stream>>>(nodes, gsum, out0);
}

// Round 3
// 305.584 us; speedup vs baseline: 2.1587x; 2.1587x over previous
//
#include <hip/hip_runtime.h>
#include <math.h>

// Problem constants (fixed by reference setup_inputs)
#define B_ 16
#define C_ 512
#define N_ 4096   // 64*64
#define K_ 64

// Workspace layout (float offsets). Total ~689K floats = 2.76 MB (< proven 4.7 MB).
#define OFF_PBIG    0         // [64 k][2048 dwords] bf16-pair packed param matrix (r = c*8+f)
#define OFF_INVSIG  131072    // [K][C] 1/sigma fp32
#define OFF_WSUM    163840    // [B][K]
#define OFF_GSUM    164864    // [B]
#define OFF_WX      164992    // [B][K][C] fp32 (written non-atomically)

typedef short bf16x8 __attribute__((ext_vector_type(8)));   // 8 bf16 in 4 VGPRs
typedef float f32x16 __attribute__((ext_vector_type(16)));  // MFMA 32x32 accumulator

union U4 { uint4 u; bf16x8 b; };

__device__ __forceinline__ unsigned hi16(float f) { return __float_as_uint(f) >> 16; }
__device__ __forceinline__ unsigned hi16rne(float f) {
  return (__float_as_uint(f) + 0x8000u) >> 16;
}
__device__ __forceinline__ float fromhi(unsigned h) { return __uint_as_float(h << 16); }
// pack two floats' truncated-bf16 into one dword: low16 = bf16(lo), high16 = bf16(hi)
__device__ __forceinline__ unsigned pk(float lo, float hi) {
  return (__float_as_uint(lo) >> 16) | (__float_as_uint(hi) & 0xFFFF0000u);
}

// ---------------------------------------------------------------- kernel 1
// Build pbig, invsig; zero wsum/gsum. One block per k.
// Feature order per c (A-side in k_dist pairs with these P rows):
//   f0: is2h   (x *: x2h)     f1: is2l (x2h)   f2: is2h (x2l)
//   f3: mh     (xh)           f4: ml   (xh)    f5: mh   (xl)
//   f6,f7 (only c==0): consth, constl  (A-side 1.0)
__global__ void k_prep(const float* __restrict__ anchor,
                       const float* __restrict__ sraw,
                       unsigned* __restrict__ pbig,
                       float* __restrict__ invsig,
                       float* __restrict__ wsum,
                       float* __restrict__ gsum) {
  const int k = blockIdx.x;
  const int t = threadIdx.x;
  __shared__ float s_is2[C_], s_m[C_];
  __shared__ float red[4];
  float part = 0.f;
#pragma unroll
  for (int r = 0; r < 2; r++) {
    int c = r * 256 + t;
    float a = anchor[k * C_ + c];
    float sg = 1.f / (1.f + __expf(-sraw[k * C_ + c]));
    float is = 1.f / sg;
    float is2 = is * is;
    s_is2[c] = is2;
    s_m[c] = -2.f * a * is2;
    invsig[k * C_ + c] = is;
    part = fmaf(a * a, is2, part);
  }
  float v = part;
#pragma unroll
  for (int off = 32; off; off >>= 1) v += __shfl_down(v, off);
  if ((t & 63) == 0) red[t >> 6] = v;
  __syncthreads();
  float cst = red[0] + red[1] + red[2] + red[3];
  unsigned ch = hi16(cst);
  unsigned clr = hi16rne(cst - fromhi(ch));
#pragma unroll
  for (int r = 0; r < 2; r++) {
    int c = r * 256 + t;
    float is2 = s_is2[c], m = s_m[c];
    unsigned ih = hi16(is2);
    unsigned ilr = hi16rne(is2 - fromhi(ih));
    unsigned mh = hi16(m);
    unsigned mlr = hi16rne(m - fromhi(mh));
    unsigned* p = pbig + (size_t)k * 2048 + c * 4;
    p[0] = ih | (ilr << 16);
    p[1] = ih | (mh << 16);
    p[2] = mlr | (mh << 16);
    p[3] = (c == 0) ? (ch | (clr << 16)) : 0u;
  }
  if (k == 0) {
    for (int i = t; i < B_ * K_; i += 256) wsum[i] = 0.f;
    if (t < B_) gsum[t] = 0.f;
  }
}

// ---------------------------------------------------------------- kernel 2
// MFMA distance GEMM (split-bf16, inner dim 4096) + in-register softmax.
// grid (N/256, B), block 256 (4 waves). Wave tile: 64k x 64n (2 kt x 2 ns).
__global__ __launch_bounds__(256) void k_dist(
    const float* __restrict__ x,
    const unsigned* __restrict__ pbig,
    float* __restrict__ soft,
    float* __restrict__ wsum) {
  const int b = blockIdx.y;
  const int nblk = blockIdx.x * 256;
  const int tid = threadIdx.x;
  const int wid = tid >> 6;
  const int lane = tid & 63;
  const int l31 = lane & 31;
  const int lh = lane >> 5;
  const int n0 = nblk + wid * 64;

  __shared__ unsigned ldsA[64 * 132];  // row stride 132 dw = 528 B (odd x16B)

  f32x16 acc[2][2];
#pragma unroll
  for (int kt = 0; kt < 2; kt++)
#pragma unroll
    for (int ns = 0; ns < 2; ns++)
#pragma unroll
      for (int i = 0; i < 16; i++) acc[kt][ns][i] = 0.f;

  const float* xb = x + (size_t)b * (C_ * N_);

  for (int chunk = 0; chunk < 16; chunk++) {
    // stage pbig r-chunk (64 k rows x 128 dwords) into LDS
    const uint4* src = (const uint4*)pbig;
#pragma unroll
    for (int it = 0; it < 8; it++) {
      int flat = tid + it * 256;       // 0..2047
      int k = flat >> 5, q = flat & 31;
      uint4 vv = src[(size_t)k * 512 + chunk * 32 + q];
      *(uint4*)&ldsA[k * 132 + q * 4] = vv;
    }
    __syncthreads();
    const int cchunk = chunk * 32;
    for (int kstep = 0; kstep < 16; kstep++) {
      U4 a0, a1;
      a0.u = *(const uint4*)&ldsA[l31 * 132 + kstep * 8 + lh * 4];
      a1.u = *(const uint4*)&ldsA[(32 + l31) * 132 + kstep * 8 + lh * 4];
      const int c = cchunk + kstep * 2 + lh;
      const float* xr = xb + (size_t)c * N_;
#pragma unroll
      for (int ns = 0; ns < 2; ns++) {
        float xv = xr[n0 + ns * 32 + l31];
        float x2 = xv * xv;
        unsigned u = __float_as_uint(xv);
        unsigned u2 = __float_as_uint(x2);
        unsigned uhf = u & 0xFFFF0000u;
        unsigned u2hf = u2 & 0xFFFF0000u;
        float xl = xv - __uint_as_float(uhf);
        float x2l = x2 - __uint_as_float(u2hf);
        U4 bf;
        bf.u.x = (u2 >> 16) | u2hf;                                   // x2h | x2h
        bf.u.y = ((__float_as_uint(x2l) + 0x8000u) >> 16) | uhf;      // x2l | xh
        bf.u.z = (u >> 16) | ((__float_as_uint(xl) + 0x8000u) & 0xFFFF0000u); // xh | xl
        bf.u.w = (c == 0) ? 0x3F803F80u : 0u;                         // 1.0 | 1.0 @ c==0
        acc[0][ns] = __builtin_amdgcn_mfma_f32_32x32x16_bf16(a0.b, bf.b, acc[0][ns], 0, 0, 0);
        acc[1][ns] = __builtin_amdgcn_mfma_f32_32x32x16_bf16(a1.b, bf.b, acc[1][ns], 0, 0, 0);
      }
    }
    __syncthreads();
  }

  // ---- softmax over k=64 per column n (lane l & l^32 hold complementary k) ----
  float* softb = soft + (size_t)b * (K_ * N_);
#pragma unroll
  for (int ns = 0; ns < 2; ns++) {
    float mm = -3.4e38f;
#pragma unroll
    for (int kt = 0; kt < 2; kt++)
#pragma unroll
      for (int r = 0; r < 16; r++) {
        float l = -0.5f * acc[kt][ns][r];
        acc[kt][ns][r] = l;
        mm = fmaxf(mm, l);
      }
    mm = fmaxf(mm, __shfl_xor(mm, 32));
    float ss = 0.f;
#pragma unroll
    for (int kt = 0; kt < 2; kt++)
#pragma unroll
      for (int r = 0; r < 16; r++) {
        float e = __expf(acc[kt][ns][r] - mm);
        acc[kt][ns][r] = e;
        ss += e;
      }
    ss += __shfl_xor(ss, 32);
    float inv = 1.f / ss;
    const int nc = n0 + ns * 32 + l31;
#pragma unroll
    for (int kt = 0; kt < 2; kt++)
#pragma unroll
      for (int r = 0; r < 16; r++) {
        float w = acc[kt][ns][r] * inv;
        acc[kt][ns][r] = w;
        int k = kt * 32 + (r & 3) + 8 * (r >> 2) + 4 * lh;
        softb[(size_t)k * N_ + nc] = w;
      }
  }
  // ---- wsum: reduce over the 32 n-columns, one atomic per (k) per half ----
#pragma unroll
  for (int kt = 0; kt < 2; kt++)
#pragma unroll
    for (int r = 0; r < 16; r++) {
      float v = acc[kt][0][r] + acc[kt][1][r];
      v += __shfl_xor(v, 1);
      v += __shfl_xor(v, 2);
      v += __shfl_xor(v, 4);
      v += __shfl_xor(v, 8);
      v += __shfl_xor(v, 16);
      if (l31 == 0) {
        int k = kt * 32 + (r & 3) + 8 * (r >> 2) + 4 * lh;
        atomicAdd(&wsum[b * K_ + k], v);
      }
    }
}

// ---------------------------------------------------------------- kernel 3
// Aggregation GEMM via MFMA: wx[b,k,c] = sum_n soft[b,k,n]*x[b,c,n].
// grid (C/32, B), block 256. Waves split n (1024 each); LDS reduce; no atomics.
__global__ __launch_bounds__(256) void k_agg(const float* __restrict__ x,
                                             const float* __restrict__ soft,
                                             float* __restrict__ wx) {
  const int ct = blockIdx.x;
  const int b = blockIdx.y;
  const int tid = threadIdx.x;
  const int wid = tid >> 6, lane = tid & 63, l31 = lane & 31, lh = lane >> 5;
  const int c0 = ct * 32;
  const int n0 = wid * 1024;
  __shared__ float red[4][64][36];  // stride 36 floats = 9x16B (odd) per lane

  f32x16 acc[2];
#pragma unroll
  for (int kt = 0; kt < 2; kt++)
#pragma unroll
    for (int i = 0; i < 16; i++) acc[kt][i] = 0.f;

  const float* sb = soft + (size_t)b * (K_ * N_);
  const float* xr = x + (size_t)b * (C_ * N_) + (size_t)(c0 + l31) * N_;
  const float* s0 = sb + (size_t)l31 * N_;
  const float* s1 = sb + (size_t)(32 + l31) * N_;

  for (int kstep = 0; kstep < 64; kstep++) {
    int nb = n0 + kstep * 16 + lh * 8;
    float4 f0 = *(const float4*)&s0[nb];
    float4 f1 = *(const float4*)&s0[nb + 4];
    float4 g0 = *(const float4*)&s1[nb];
    float4 g1 = *(const float4*)&s1[nb + 4];
    float4 h0 = *(const float4*)&xr[nb];
    float4 h1 = *(const float4*)&xr[nb + 4];
    U4 A0, A1, Bf;
    A0.u.x = pk(f0.x, f0.y); A0.u.y = pk(f0.z, f0.w);
    A0.u.z = pk(f1.x, f1.y); A0.u.w = pk(f1.z, f1.w);
    A1.u.x = pk(g0.x, g0.y); A1.u.y = pk(g0.z, g0.w);
    A1.u.z = pk(g1.x, g1.y); A1.u.w = pk(g1.z, g1.w);
    Bf.u.x = pk(h0.x, h0.y); Bf.u.y = pk(h0.z, h0.w);
    Bf.u.z = pk(h1.x, h1.y); Bf.u.w = pk(h1.z, h1.w);
    acc[0] = __builtin_amdgcn_mfma_f32_32x32x16_bf16(A0.b, Bf.b, acc[0], 0, 0, 0);
    acc[1] = __builtin_amdgcn_mfma_f32_32x32x16_bf16(A1.b, Bf.b, acc[1], 0, 0, 0);
  }
  // stash per-wave partials
#pragma unroll
  for (int kt = 0; kt < 2; kt++)
#pragma unroll
    for (int q = 0; q < 4; q++) {
      float4 vv = make_float4(acc[kt][q * 4], acc[kt][q * 4 + 1],
                              acc[kt][q * 4 + 2], acc[kt][q * 4 + 3]);
      *(float4*)&red[wid][lane][kt * 16 + q * 4] = vv;
    }
  __syncthreads();
  // cross-wave reduce + write (2048 outputs, 8 per thread)
  const int lt = tid & 63, sb4 = (tid >> 6) * 8;
  float v[8];
#pragma unroll
  for (int i = 0; i < 8; i++) v[i] = 0.f;
#pragma unroll
  for (int w = 0; w < 4; w++)
#pragma unroll
    for (int i = 0; i < 8; i++) v[i] += red[w][lt][sb4 + i];
#pragma unroll
  for (int i = 0; i < 8; i++) {
    int s = sb4 + i;
    int kt = s >> 4, r = s & 15;
    int k = kt * 32 + (r & 3) + 8 * (r >> 2) + 4 * (lt >> 5);
    wx[((size_t)b * K_ + k) * C_ + c0 + (lt & 31)] = v[i];
  }
}

// ---------------------------------------------------------------- kernel 4
// nodes = (wx - wsum*anchor)/sigma/(wsum+eps); intra L2-norm -> out0; gsum.
__global__ void k_nodes(const float* __restrict__ wx,
                        const float* __restrict__ wsum,
                        const float* __restrict__ anchor,
                        const float* __restrict__ invsig,
                        float* __restrict__ out0,
                        float* __restrict__ gsum) {
  const int k = blockIdx.x, b = blockIdx.y;
  const int tid = threadIdx.x;
  float wsv = wsum[b * K_ + k];
  float winv = 1.f / (wsv + 1e-9f);
  float vals[4];
  float local = 0.f;
#pragma unroll
  for (int r = 0; r < 4; r++) {
    int c = r * 128 + tid;
    float w = wx[((size_t)b * K_ + k) * C_ + c];
    float v = (w - wsv * anchor[k * C_ + c]) * invsig[k * C_ + c] * winv;
    vals[r] = v;
    local = fmaf(v, v, local);
  }
  float v = local;
#pragma unroll
  for (int off = 32; off; off >>= 1) v += __shfl_down(v, off);
  __shared__ float red[2];
  if ((tid & 63) == 0) red[tid >> 6] = v;
  __syncthreads();
  float sumsq = red[0] + red[1];
  float norm = sqrtf(sumsq);
  float scale = 1.f / fmaxf(norm, 1e-12f);
#pragma unroll
  for (int r = 0; r < 4; r++) {
    int c = r * 128 + tid;
    out0[((size_t)b * K_ + k) * C_ + c] = vals[r] * scale;
  }
  if (tid == 0) atomicAdd(&gsum[b], sumsq * scale * scale);
}

// ---------------------------------------------------------------- kernel 5
// Global L2 scale in place on out0 ([B][K*C] flat == reference (B,C,K)).
__global__ void k_final(float* __restrict__ out0,
                        const float* __restrict__ gsum) {
  for (int i = blockIdx.x * 256 + threadIdx.x; i < B_ * K_ * C_;
       i += gridDim.x * 256) {
    int b = i >> 15;  // K_*C_ = 32768
    out0[i] = out0[i] * (1.f / fmaxf(sqrtf(gsum[b]), 1e-12f));
  }
}

// ---------------------------------------------------------------- launch
extern "C" void kernel_launch(void* const* d_in, const int* in_sizes, int n_in,
                              void* d_out, int out_size, void* d_ws, size_t ws_size,
                              hipStream_t stream) {
  const float* x = (const float*)d_in[0];       // [B,C,H,W]
  const float* anchor = (const float*)d_in[1];  // [K,C]
  const float* sraw = (const float*)d_in[2];    // [K,C]
  float* out0 = (float*)d_out;                          // [B,C,K] flat
  float* soft = out0 + (size_t)B_ * C_ * K_;            // [B,K,N] (output 1)
  float* ws = (float*)d_ws;

  unsigned* pbig = (unsigned*)(ws + OFF_PBIG);
  float* invsig = ws + OFF_INVSIG;
  float* wsum = ws + OFF_WSUM;
  float* gsum = ws + OFF_GSUM;
  float* wx = ws + OFF_WX;

  k_prep<<<K_, 256, 0, stream>>>(anchor, sraw, pbig, invsig, wsum, gsum);
  k_dist<<<dim3(N_ / 256, B_), 256, 0, stream>>>(x, pbig, soft, wsum);
  k_agg<<<dim3(C_ / 32, B_), 256, 0, stream>>>(x, soft, wx);
  k_nodes<<<dim3(K_, B_), 128, 0, stream>>>(wx, wsum, anchor, invsig, out0,
                                            gsum);
  k_final<<<512, 256, 0, stream>>>(out0, gsum);
}